// Round 1
// baseline (1708.985 us; speedup 1.0000x reference)
//
#include <hip/hip_runtime.h>
#include <math.h>

#define BB 2
#define LL 1024
#define DD 768
#define DI 1536
#define NS 16
#define DRR 48
#define KC 4
#define VOC 32000
#define BT (BB*LL)          // 2048 rows
#define EPS 1e-5f

typedef __attribute__((ext_vector_type(4))) float f32x4;
typedef __attribute__((ext_vector_type(8))) short short8;

__device__ __forceinline__ unsigned short f2bf(float f) {
    unsigned int u = __float_as_uint(f);
    u += 0x7FFFu + ((u >> 16) & 1u);   // RNE
    return (unsigned short)(u >> 16);
}

// ---------------------------------------------------------------------------
// Generic C = A(MxK) * W(NxK)^T  [+ C], fp32 in/out, bf16 MFMA inside.
// Tile 128x128x32, 256 threads (4 waves, each 64x64 via 4x4 of 16x16x32).
// ---------------------------------------------------------------------------
template<bool ADD, bool NMASK>
__global__ __launch_bounds__(256) void gemm_kernel(
    const float* __restrict__ A, const float* __restrict__ W,
    float* C, int Nn, int K, int lda, int ldw, int ldc)
{
    __shared__ __align__(16) unsigned short As[128][32];
    __shared__ __align__(16) unsigned short Ws[128][32];

    const int row0 = blockIdx.x * 128;
    const int col0 = blockIdx.y * 128;
    const int tid  = threadIdx.x;
    const int lane = tid & 63;
    const int wave = tid >> 6;
    const int wm   = (wave & 1) * 64;
    const int wn   = (wave >> 1) * 64;
    const int mrow = lane & 15;
    const int quad = lane >> 4;

    f32x4 acc[4][4];
#pragma unroll
    for (int i = 0; i < 4; ++i)
#pragma unroll
        for (int j = 0; j < 4; ++j)
            acc[i][j] = (f32x4){0.f, 0.f, 0.f, 0.f};

    for (int k0 = 0; k0 < K; k0 += 32) {
#pragma unroll
        for (int c = 0; c < 4; ++c) {
            int idx = (tid + c * 256) * 4;     // 0..4095
            int r   = idx >> 5;                // 0..127
            int col = idx & 31;                // 0,4,...,28
            int gk  = k0 + col;
            float4 va = *(const float4*)(A + (size_t)(row0 + r) * lda + gk);
            float4 vw = {0.f, 0.f, 0.f, 0.f};
            int wr = col0 + r;
            if (!NMASK || wr < Nn)
                vw = *(const float4*)(W + (size_t)wr * ldw + gk);
            ushort4 pa, pw;
            pa.x = f2bf(va.x); pa.y = f2bf(va.y); pa.z = f2bf(va.z); pa.w = f2bf(va.w);
            pw.x = f2bf(vw.x); pw.y = f2bf(vw.y); pw.z = f2bf(vw.z); pw.w = f2bf(vw.w);
            *(ushort4*)&As[r][col] = pa;
            *(ushort4*)&Ws[r][col] = pw;
        }
        __syncthreads();

        short8 af[4], wf[4];
#pragma unroll
        for (int i = 0; i < 4; ++i) {
            af[i] = *(const short8*)&As[wm + i * 16 + mrow][quad * 8];
            wf[i] = *(const short8*)&Ws[wn + i * 16 + mrow][quad * 8];
        }
#pragma unroll
        for (int i = 0; i < 4; ++i)
#pragma unroll
            for (int j = 0; j < 4; ++j)
                acc[i][j] = __builtin_amdgcn_mfma_f32_16x16x32_bf16(
                    af[i], wf[j], acc[i][j], 0, 0, 0);
        __syncthreads();
    }

    // epilogue: C/D layout col=lane&15, row=quad*4+r  [verified m89]
#pragma unroll
    for (int i = 0; i < 4; ++i)
#pragma unroll
        for (int j = 0; j < 4; ++j)
#pragma unroll
            for (int r = 0; r < 4; ++r) {
                int row = row0 + wm + i * 16 + quad * 4 + r;
                int col = col0 + wn + j * 16 + mrow;
                if (!NMASK || col < Nn) {
                    float v = acc[i][j][r];
                    if (ADD) v += C[(size_t)row * ldc + col];
                    C[(size_t)row * ldc + col] = v;
                }
            }
}

// ---------------------------------------------------------------------------
__global__ __launch_bounds__(256) void embed_kernel(
    const int* __restrict__ x, const float* __restrict__ emb, float* __restrict__ h)
{
    int idx = blockIdx.x * 256 + threadIdx.x;          // over BT * D/4
    if (idx >= BT * (DD / 4)) return;
    int row = idx / (DD / 4), c = idx % (DD / 4);
    ((float4*)h)[idx] = ((const float4*)(emb + (size_t)x[row] * DD))[c];
}

__global__ __launch_bounds__(256) void rmsnorm_kernel(
    const float* __restrict__ h, const float* __restrict__ w, float* __restrict__ out)
{
    int row = blockIdx.x, tid = threadIdx.x;
    const float* hr = h + (size_t)row * DD;
    float s = 0.f;
    for (int i = tid; i < DD; i += 256) { float v = hr[i]; s += v * v; }
#pragma unroll
    for (int off = 32; off >= 1; off >>= 1) s += __shfl_xor(s, off);
    __shared__ float part[4];
    if ((tid & 63) == 0) part[tid >> 6] = s;
    __syncthreads();
    float tot = part[0] + part[1] + part[2] + part[3];
    float sc = rsqrtf(tot * (1.0f / DD) + EPS);
    for (int i = tid; i < DD; i += 256)
        out[(size_t)row * DD + i] = hr[i] * sc * w[i];
}

// xi = silu(causal_conv(xz[:, :DI]) + cb)
__global__ __launch_bounds__(256) void conv_silu_kernel(
    const float* __restrict__ xz, const float* __restrict__ cw,
    const float* __restrict__ cb, float* __restrict__ xi)
{
    int idx = blockIdx.x * 256 + threadIdx.x;  // over BT*DI
    if (idx >= BT * DI) return;
    int d = idx % DI, bt = idx / DI, t = bt % LL;
    const float* base = xz + (size_t)bt * (2 * DI) + d;
    float w0 = cw[d * 4 + 0], w1 = cw[d * 4 + 1], w2 = cw[d * 4 + 2], w3 = cw[d * 4 + 3];
    float acc = cb[d] + base[0] * w3;                       // k=3 -> h[t]
    if (t >= 1) acc += base[-(size_t)(2 * DI)]     * w2;    // h[t-1]
    if (t >= 2) acc += base[-(size_t)(4 * DI)]     * w1;    // h[t-2]
    if (t >= 3) acc += base[-(size_t)(6 * DI)]     * w0;    // h[t-3]
    xi[idx] = acc / (1.0f + expf(-acc));                    // silu
}

// delta = softplus(dlt @ dw^T + db); dlt = bcd[:, 32:80]
__global__ __launch_bounds__(256) void delta_kernel(
    const float* __restrict__ bcd, const float* __restrict__ dw,
    const float* __restrict__ db, float* __restrict__ delta)
{
    int row = blockIdx.x / 6, chunk = blockIdx.x % 6;
    int d = chunk * 256 + threadIdx.x;
    __shared__ float dlt_s[DRR];
    if (threadIdx.x < DRR) dlt_s[threadIdx.x] = bcd[(size_t)row * 80 + 32 + threadIdx.x];
    __syncthreads();
    float z = db[d];
    const float* wr = dw + (size_t)d * DRR;
#pragma unroll
    for (int r = 0; r < DRR; ++r) z = fmaf(dlt_s[r], wr[r], z);
    delta[(size_t)row * DI + d] = (z > 20.f) ? z : log1pf(expf(z));
}

// S6 scan: grid = BB * (DI/16) blocks, 256 threads = 4 waves * (4 d x 16 n)
#define TCH 64
__global__ __launch_bounds__(256) void scan_kernel(
    const float* __restrict__ delta, const float* __restrict__ xi,
    const float* __restrict__ bcd, const float* __restrict__ lA,
    const float* __restrict__ Dp, float* __restrict__ y)
{
    int blk  = blockIdx.x;
    int b    = blk / (DI / 16);
    int dblk = (blk % (DI / 16)) * 16;
    int tid  = threadIdx.x;
    int lane = tid & 63, wave = tid >> 6;
    int n  = lane & 15;
    int dl = wave * 4 + (lane >> 4);   // 0..15 in block
    int d  = dblk + dl;

    float Av   = -expf(lA[(size_t)d * NS + n]);
    float A2   = Av * 1.44269504088896f;      // for exp2
    float invA = 1.0f / Av;
    float Dpv  = Dp[d];
    float hs   = 0.f;

    __shared__ float s_dlt[TCH][16];
    __shared__ float s_xi [TCH][16];
    __shared__ float s_B  [TCH][16];
    __shared__ float s_C  [TCH][16];

    const float* dbase  = delta + (size_t)b * LL * DI + dblk;
    const float* xbase  = xi    + (size_t)b * LL * DI + dblk;
    const float* bcbase = bcd   + (size_t)b * LL * 80;
    float*       ybase  = y     + (size_t)b * LL * DI + dblk;

    for (int t0 = 0; t0 < LL; t0 += TCH) {
        __syncthreads();
        for (int i = tid; i < TCH * 16; i += 256) {
            int tt = i >> 4, dd = i & 15;
            s_dlt[tt][dd] = dbase[(size_t)(t0 + tt) * DI + dd];
            s_xi [tt][dd] = xbase[(size_t)(t0 + tt) * DI + dd];
            s_B  [tt][dd] = bcbase[(size_t)(t0 + tt) * 80 + dd];
            s_C  [tt][dd] = bcbase[(size_t)(t0 + tt) * 80 + 16 + dd];
        }
        __syncthreads();
#pragma unroll 4
        for (int tt = 0; tt < TCH; ++tt) {
            float dv = s_dlt[tt][dl];
            float xv = s_xi [tt][dl];
            float Bv = s_B  [tt][n];
            float Cv = s_C  [tt][n];
            float Ab = exp2f(dv * A2);
            float u  = (Ab - 1.0f) * invA * Bv * xv;
            hs = fmaf(Ab, hs, u);
            float c = Cv * hs;
            c += __shfl_xor(c, 1);
            c += __shfl_xor(c, 2);
            c += __shfl_xor(c, 4);
            c += __shfl_xor(c, 8);
            if (n == 0) ybase[(size_t)(t0 + tt) * DI + dl] = fmaf(xv, Dpv, c);
        }
    }
}

// y *= silu(xz[:, DI:2*DI])
__global__ __launch_bounds__(256) void gate_kernel(
    float* __restrict__ y, const float* __restrict__ xz)
{
    int idx = blockIdx.x * 256 + threadIdx.x;
    if (idx >= BT * DI) return;
    int d = idx % DI, bt = idx / DI;
    float r = xz[(size_t)bt * (2 * DI) + DI + d];
    y[idx] *= r / (1.0f + expf(-r));
}

// ---------------------------------------------------------------------------
extern "C" void kernel_launch(void* const* d_in, const int* in_sizes, int n_in,
                              void* d_out, int out_size, void* d_ws, size_t ws_size,
                              hipStream_t stream)
{
    const int*   x    = (const int*)  d_in[0];
    const float* emb  = (const float*)d_in[1];
    const float* rmsw = (const float*)d_in[2];
    const float* inw  = (const float*)d_in[3];
    const float* cw   = (const float*)d_in[4];
    const float* cb   = (const float*)d_in[5];
    const float* lA   = (const float*)d_in[6];
    const float* bcw  = (const float*)d_in[7];
    const float* dw   = (const float*)d_in[8];
    const float* db   = (const float*)d_in[9];
    const float* Dp   = (const float*)d_in[10];
    const float* ow   = (const float*)d_in[11];
    const float* nfw  = (const float*)d_in[12];
    float* out = (float*)d_out;

    float* ws = (float*)d_ws;
    float* h    = ws;                       // BT*DD
    float* hn   = h    + (size_t)BT * DD;   // BT*DD
    float* xz   = hn   + (size_t)BT * DD;   // BT*2*DI
    float* xib  = xz   + (size_t)BT * 2 * DI; // BT*DI
    float* bcd  = xib  + (size_t)BT * DI;   // BT*80
    float* dlt  = bcd  + (size_t)BT * 80;   // BT*DI
    float* yb   = dlt  + (size_t)BT * DI;   // BT*DI

    embed_kernel<<<(BT * (DD / 4) + 255) / 256, 256, 0, stream>>>(x, emb, h);

    for (int layer = 0; layer < 2; ++layer) {
        rmsnorm_kernel<<<BT, 256, 0, stream>>>(h, rmsw + (size_t)layer * DD, hn);

        // xz = hn @ in_w^T : M=2048 N=3072 K=768
        gemm_kernel<false, false><<<dim3(BT / 128, 2 * DI / 128), 256, 0, stream>>>(
            hn, inw + (size_t)layer * 2 * DI * DD, xz, 2 * DI, DD, DD, DD, 2 * DI);

        conv_silu_kernel<<<(BT * DI + 255) / 256, 256, 0, stream>>>(
            xz, cw + (size_t)layer * DI * KC, cb + (size_t)layer * DI, xib);

        // bcd = xi @ bcw^T : M=2048 N=80 K=1536
        gemm_kernel<false, true><<<dim3(BT / 128, 1), 256, 0, stream>>>(
            xib, bcw + (size_t)layer * 80 * DI, bcd, 80, DI, DI, DI, 80);

        delta_kernel<<<BT * 6, 256, 0, stream>>>(
            bcd, dw + (size_t)layer * DI * DRR, db + (size_t)layer * DI, dlt);

        scan_kernel<<<BB * (DI / 16), 256, 0, stream>>>(
            dlt, xib, bcd, lA + (size_t)layer * DI * NS, Dp + (size_t)layer * DI, yb);

        gate_kernel<<<(BT * DI + 255) / 256, 256, 0, stream>>>(yb, xz);

        // h += y @ ow^T : M=2048 N=768 K=1536
        gemm_kernel<true, false><<<dim3(BT / 128, DD / 128), 256, 0, stream>>>(
            yb, ow + (size_t)layer * DD * DI, h, DD, DI, DI, DI, DD);
    }

    rmsnorm_kernel<<<BT, 256, 0, stream>>>(h, nfw, hn);

    // logits = hn @ emb^T : M=2048 N=32000 K=768
    gemm_kernel<false, false><<<dim3(BT / 128, VOC / 128), 256, 0, stream>>>(
        hn, emb, out, VOC, DD, DD, DD, VOC);
}

// Round 2
// 1329.411 us; speedup vs baseline: 1.2855x; 1.2855x over previous
//
#include <hip/hip_runtime.h>
#include <math.h>

#define BB 2
#define LL 1024
#define DD 768
#define DI 1536
#define NS 16
#define DRR 48
#define KC 4
#define VOC 32000
#define BT (BB*LL)          // 2048 rows
#define EPS 1e-5f

typedef __attribute__((ext_vector_type(4))) float f32x4;
typedef __attribute__((ext_vector_type(8))) short short8;
typedef unsigned short ushort_t;

__device__ __forceinline__ unsigned short f2bf(float f) {
    unsigned int u = __float_as_uint(f);
    u += 0x7FFFu + ((u >> 16) & 1u);   // RNE
    return (unsigned short)(u >> 16);
}

// async global->LDS, 16B per lane; lds base must be wave-uniform, HW adds lane*16
#define GLDS(gp, lp) __builtin_amdgcn_global_load_lds( \
    (const __attribute__((address_space(1))) unsigned int*)(gp), \
    (__attribute__((address_space(3))) unsigned int*)(lp), 16, 0, 0)

// ---------------------------------------------------------------------------
// C = A(MxK,bf16) * W(NxK,bf16)^T [+C / atomic], fp32 out.
// m97 structure: 128x128 tile, BK=32, global_load_lds width-16 staging.
// grid.z = split-K chunks of kchunk.
// ---------------------------------------------------------------------------
template<bool ADD, bool NMASK, bool ATOMIC>
__global__ __launch_bounds__(256) void gemm_bf16(
    const ushort_t* __restrict__ A, const ushort_t* __restrict__ W,
    float* C, int Nn, int lda, int ldc, int kchunk)
{
    __shared__ __align__(16) ushort_t As[128 * 32];
    __shared__ __align__(16) ushort_t Ws[128 * 32];

    const int row0 = blockIdx.x * 128;
    const int col0 = blockIdx.y * 128;
    const int tid  = threadIdx.x;
    const int lane = tid & 63;
    const int wave = tid >> 6;
    const int wm   = (wave & 1) * 64;
    const int wn   = (wave >> 1) * 64;
    const int mrow = lane & 15;
    const int quad = lane >> 4;

    const int kb = blockIdx.z * kchunk;

    // staging address precompute: slot s = r*256+tid -> row = 64r + tid/4, col8 = (tid%4)*8
    const int srow = tid >> 2;
    const int scol = (tid & 3) << 3;
    const ushort_t* gA0 = A + (size_t)(row0 + srow) * lda + scol;
    const ushort_t* gA1 = A + (size_t)(row0 + 64 + srow) * lda + scol;
    const ushort_t* gW0 = W + (size_t)(col0 + srow) * lda + scol;
    const ushort_t* gW1 = W + (size_t)(col0 + 64 + srow) * lda + scol;
    char* lA0 = (char*)As + wave * 1024;
    char* lA1 = (char*)As + 4096 + wave * 1024;
    char* lW0 = (char*)Ws + wave * 1024;
    char* lW1 = (char*)Ws + 4096 + wave * 1024;

    f32x4 acc[4][4];
#pragma unroll
    for (int i = 0; i < 4; ++i)
#pragma unroll
        for (int j = 0; j < 4; ++j)
            acc[i][j] = (f32x4){0.f, 0.f, 0.f, 0.f};

    for (int k0 = kb; k0 < kb + kchunk; k0 += 32) {
        GLDS(gA0 + k0, lA0);
        GLDS(gA1 + k0, lA1);
        GLDS(gW0 + k0, lW0);
        GLDS(gW1 + k0, lW1);
        __syncthreads();   // compiler emits vmcnt(0) drain before barrier

        short8 af[4], wf[4];
#pragma unroll
        for (int i = 0; i < 4; ++i) {
            af[i] = *(const short8*)&As[(wm + i * 16 + mrow) * 32 + quad * 8];
            wf[i] = *(const short8*)&Ws[(wn + i * 16 + mrow) * 32 + quad * 8];
        }
#pragma unroll
        for (int i = 0; i < 4; ++i)
#pragma unroll
            for (int j = 0; j < 4; ++j)
                acc[i][j] = __builtin_amdgcn_mfma_f32_16x16x32_bf16(
                    af[i], wf[j], acc[i][j], 0, 0, 0);
        __syncthreads();
    }

    // epilogue: C/D layout col=lane&15, row=quad*4+r  [verified m89]
#pragma unroll
    for (int i = 0; i < 4; ++i)
#pragma unroll
        for (int j = 0; j < 4; ++j)
#pragma unroll
            for (int r = 0; r < 4; ++r) {
                int row = row0 + wm + i * 16 + quad * 4 + r;
                int col = col0 + wn + j * 16 + mrow;
                if (!NMASK || col < Nn) {
                    float v = acc[i][j][r];
                    size_t off = (size_t)row * ldc + col;
                    if (ATOMIC) {
                        atomicAdd(&C[off], v);
                    } else {
                        if (ADD) v += C[off];
                        C[off] = v;
                    }
                }
            }
}

// ---------------------------------------------------------------------------
__global__ __launch_bounds__(256) void cvt_bf16_kernel(
    const float* __restrict__ in, ushort_t* __restrict__ out, int n4)
{
    int i = blockIdx.x * 256 + threadIdx.x;
    if (i >= n4) return;
    float4 v = ((const float4*)in)[i];
    ushort4 o;
    o.x = f2bf(v.x); o.y = f2bf(v.y); o.z = f2bf(v.z); o.w = f2bf(v.w);
    ((ushort4*)out)[i] = o;
}

// bcdelta_w (2 x 80 x 1536) -> padded (2 x 128 x 1536) bf16, zero rows 80..127
__global__ __launch_bounds__(256) void cvt_bcw_kernel(
    const float* __restrict__ bcw, ushort_t* __restrict__ out)
{
    int i = blockIdx.x * 256 + threadIdx.x;   // over 2*128*1536/4
    if (i >= 2 * 128 * 1536 / 4) return;
    int e = i * 4;
    int layer = e / (128 * 1536);
    int rem = e % (128 * 1536);
    int row = rem / 1536, col = rem % 1536;
    ushort4 o = {0, 0, 0, 0};
    if (row < 80) {
        float4 v = *(const float4*)(bcw + ((size_t)layer * 80 + row) * 1536 + col);
        o.x = f2bf(v.x); o.y = f2bf(v.y); o.z = f2bf(v.z); o.w = f2bf(v.w);
    }
    ((ushort4*)out)[i] = o;
}

__global__ __launch_bounds__(256) void zero_kernel(float* __restrict__ p, int n)
{
    int i = blockIdx.x * 256 + threadIdx.x;
    if (i < n) p[i] = 0.f;
}

// ---------------------------------------------------------------------------
__global__ __launch_bounds__(256) void embed_kernel(
    const int* __restrict__ x, const float* __restrict__ emb, float* __restrict__ h)
{
    int idx = blockIdx.x * 256 + threadIdx.x;          // over BT * D/4
    if (idx >= BT * (DD / 4)) return;
    int row = idx / (DD / 4), c = idx % (DD / 4);
    ((float4*)h)[idx] = ((const float4*)(emb + (size_t)x[row] * DD))[c];
}

// rmsnorm, bf16 output (feeds GEMM A)
__global__ __launch_bounds__(256) void rmsnorm_kernel(
    const float* __restrict__ h, const float* __restrict__ w, ushort_t* __restrict__ out)
{
    int row = blockIdx.x, tid = threadIdx.x;
    const float* hr = h + (size_t)row * DD;
    float s = 0.f;
    for (int i = tid; i < DD; i += 256) { float v = hr[i]; s += v * v; }
#pragma unroll
    for (int off = 32; off >= 1; off >>= 1) s += __shfl_xor(s, off);
    __shared__ float part[4];
    if ((tid & 63) == 0) part[tid >> 6] = s;
    __syncthreads();
    float tot = part[0] + part[1] + part[2] + part[3];
    float sc = rsqrtf(tot * (1.0f / DD) + EPS);
    for (int i = tid; i < DD; i += 256)
        out[(size_t)row * DD + i] = f2bf(hr[i] * sc * w[i]);
}

// xi = silu(causal_conv(xz[:, :DI]) + cb); writes fp32 (scan) + bf16 (GEMM A)
__global__ __launch_bounds__(256) void conv_silu_kernel(
    const float* __restrict__ xz, const float* __restrict__ cw,
    const float* __restrict__ cb, float* __restrict__ xi, ushort_t* __restrict__ xi16)
{
    int idx = blockIdx.x * 256 + threadIdx.x;  // over BT*DI
    if (idx >= BT * DI) return;
    int d = idx % DI, bt = idx / DI, t = bt % LL;
    const float* base = xz + (size_t)bt * (2 * DI) + d;
    float w0 = cw[d * 4 + 0], w1 = cw[d * 4 + 1], w2 = cw[d * 4 + 2], w3 = cw[d * 4 + 3];
    float acc = cb[d] + base[0] * w3;
    if (t >= 1) acc += base[-(ptrdiff_t)(2 * DI)] * w2;
    if (t >= 2) acc += base[-(ptrdiff_t)(4 * DI)] * w1;
    if (t >= 3) acc += base[-(ptrdiff_t)(6 * DI)] * w0;
    float v = acc / (1.0f + expf(-acc));
    xi[idx] = v;
    xi16[idx] = f2bf(v);
}

// delta = softplus(bcd[:,32:80] @ dw^T + db)
__global__ __launch_bounds__(256) void delta_kernel(
    const float* __restrict__ bcd, const float* __restrict__ dw,
    const float* __restrict__ db, float* __restrict__ delta)
{
    int row = blockIdx.x / 6, chunk = blockIdx.x % 6;
    int d = chunk * 256 + threadIdx.x;
    __shared__ float dlt_s[DRR];
    if (threadIdx.x < DRR) dlt_s[threadIdx.x] = bcd[(size_t)row * 80 + 32 + threadIdx.x];
    __syncthreads();
    float z = db[d];
    const float* wr = dw + (size_t)d * DRR;
#pragma unroll
    for (int r = 0; r < DRR; ++r) z = fmaf(dlt_s[r], wr[r], z);
    delta[(size_t)row * DI + d] = (z > 20.f) ? z : log1pf(expf(z));
}

// S6 scan: grid = BB * (DI/16), 256 threads = (16 d x 16 n)
#define TCH 64
__global__ __launch_bounds__(256) void scan_kernel(
    const float* __restrict__ delta, const float* __restrict__ xi,
    const float* __restrict__ bcd, const float* __restrict__ lA,
    const float* __restrict__ Dp, float* __restrict__ y)
{
    int blk  = blockIdx.x;
    int b    = blk / (DI / 16);
    int dblk = (blk % (DI / 16)) * 16;
    int tid  = threadIdx.x;
    int lane = tid & 63, wave = tid >> 6;
    int n  = lane & 15;
    int dl = wave * 4 + (lane >> 4);
    int d  = dblk + dl;

    float Av   = -expf(lA[(size_t)d * NS + n]);
    float A2   = Av * 1.44269504088896f;
    float invA = 1.0f / Av;
    float Dpv  = Dp[d];
    float hs   = 0.f;

    __shared__ float s_dlt[TCH][16];
    __shared__ float s_xi [TCH][16];
    __shared__ float s_B  [TCH][16];
    __shared__ float s_C  [TCH][16];

    const float* dbase  = delta + (size_t)b * LL * DI + dblk;
    const float* xbase  = xi    + (size_t)b * LL * DI + dblk;
    const float* bcbase = bcd   + (size_t)b * LL * 80;
    float*       ybase  = y     + (size_t)b * LL * DI + dblk;

    for (int t0 = 0; t0 < LL; t0 += TCH) {
        __syncthreads();
        for (int i = tid; i < TCH * 16; i += 256) {
            int tt = i >> 4, dd = i & 15;
            s_dlt[tt][dd] = dbase[(size_t)(t0 + tt) * DI + dd];
            s_xi [tt][dd] = xbase[(size_t)(t0 + tt) * DI + dd];
            s_B  [tt][dd] = bcbase[(size_t)(t0 + tt) * 80 + dd];
            s_C  [tt][dd] = bcbase[(size_t)(t0 + tt) * 80 + 16 + dd];
        }
        __syncthreads();
#pragma unroll 4
        for (int tt = 0; tt < TCH; ++tt) {
            float dv = s_dlt[tt][dl];
            float xv = s_xi [tt][dl];
            float Bv = s_B  [tt][n];
            float Cv = s_C  [tt][n];
            float Ab = exp2f(dv * A2);
            float u  = (Ab - 1.0f) * invA * Bv * xv;
            hs = fmaf(Ab, hs, u);
            float c = Cv * hs;
            c += __shfl_xor(c, 1);
            c += __shfl_xor(c, 2);
            c += __shfl_xor(c, 4);
            c += __shfl_xor(c, 8);
            if (n == 0) ybase[(size_t)(t0 + tt) * DI + dl] = fmaf(xv, Dpv, c);
        }
    }
}

// yg16 = bf16( y * silu(xz[:, DI:2*DI]) )
__global__ __launch_bounds__(256) void gate_kernel(
    const float* __restrict__ y, const float* __restrict__ xz, ushort_t* __restrict__ yg16)
{
    int idx = blockIdx.x * 256 + threadIdx.x;
    if (idx >= BT * DI) return;
    int d = idx % DI, bt = idx / DI;
    float r = xz[(size_t)bt * (2 * DI) + DI + d];
    yg16[idx] = f2bf(y[idx] * r / (1.0f + expf(-r)));
}

// ---------------------------------------------------------------------------
extern "C" void kernel_launch(void* const* d_in, const int* in_sizes, int n_in,
                              void* d_out, int out_size, void* d_ws, size_t ws_size,
                              hipStream_t stream)
{
    const int*   x    = (const int*)  d_in[0];
    const float* emb  = (const float*)d_in[1];
    const float* rmsw = (const float*)d_in[2];
    const float* inw  = (const float*)d_in[3];
    const float* cw   = (const float*)d_in[4];
    const float* cb   = (const float*)d_in[5];
    const float* lA   = (const float*)d_in[6];
    const float* bcw  = (const float*)d_in[7];
    const float* dw   = (const float*)d_in[8];
    const float* db   = (const float*)d_in[9];
    const float* Dp   = (const float*)d_in[10];
    const float* ow   = (const float*)d_in[11];
    const float* nfw  = (const float*)d_in[12];
    float* out = (float*)d_out;

    float* ws = (float*)d_ws;
    float* h    = ws;                          // BT*DD
    float* xz   = h    + (size_t)BT * DD;      // BT*2*DI
    float* xi   = xz   + (size_t)BT * 2 * DI;  // BT*DI
    float* bcd  = xi   + (size_t)BT * DI;      // BT*80
    float* dlt  = bcd  + (size_t)BT * 80;      // BT*DI
    float* yb   = dlt  + (size_t)BT * DI;      // BT*DI
    ushort_t* bf = (ushort_t*)(yb + (size_t)BT * DI);
    ushort_t* hn_bf  = bf;                                  // BT*DD
    ushort_t* xib_bf = hn_bf  + (size_t)BT * DD;            // BT*DI
    ushort_t* yg_bf  = xib_bf + (size_t)BT * DI;            // BT*DI
    ushort_t* emb_bf = yg_bf  + (size_t)BT * DI;            // VOC*DD
    ushort_t* inw_bf = emb_bf + (size_t)VOC * DD;           // 2*2DI*DD
    ushort_t* ow_bf  = inw_bf + (size_t)2 * 2 * DI * DD;    // 2*DD*DI
    ushort_t* bcw_bf = ow_bf  + (size_t)2 * DD * DI;        // 2*128*1536

    // weight conversions (per call; ws is re-poisoned each launch)
    cvt_bf16_kernel<<<(VOC * DD / 4 + 255) / 256, 256, 0, stream>>>(emb, emb_bf, VOC * DD / 4);
    cvt_bf16_kernel<<<(2 * 2 * DI * DD / 4 + 255) / 256, 256, 0, stream>>>(inw, inw_bf, 2 * 2 * DI * DD / 4);
    cvt_bf16_kernel<<<(2 * DD * DI / 4 + 255) / 256, 256, 0, stream>>>(ow, ow_bf, 2 * DD * DI / 4);
    cvt_bcw_kernel<<<(2 * 128 * 1536 / 4 + 255) / 256, 256, 0, stream>>>(bcw, bcw_bf);

    embed_kernel<<<(BT * (DD / 4) + 255) / 256, 256, 0, stream>>>(x, emb, h);

    for (int layer = 0; layer < 2; ++layer) {
        rmsnorm_kernel<<<BT, 256, 0, stream>>>(h, rmsw + (size_t)layer * DD, hn_bf);

        // xz = hn @ in_w^T : M=2048 N=3072 K=768
        gemm_bf16<false, false, false><<<dim3(BT / 128, 2 * DI / 128, 1), 256, 0, stream>>>(
            hn_bf, inw_bf + (size_t)layer * 2 * DI * DD, xz, 2 * DI, DD, 2 * DI, DD);

        conv_silu_kernel<<<(BT * DI + 255) / 256, 256, 0, stream>>>(
            xz, cw + (size_t)layer * DI * KC, cb + (size_t)layer * DI, xi, xib_bf);

        zero_kernel<<<(BT * 80 + 255) / 256, 256, 0, stream>>>(bcd, BT * 80);

        // bcd = xi @ bcw^T : M=2048 N=80(pad128) K=1536, split-K=8
        gemm_bf16<false, true, true><<<dim3(BT / 128, 1, 8), 256, 0, stream>>>(
            xib_bf, bcw_bf + (size_t)layer * 128 * 1536, bcd, 80, DI, 80, DI / 8);

        delta_kernel<<<BT * 6, 256, 0, stream>>>(
            bcd, dw + (size_t)layer * DI * DRR, db + (size_t)layer * DI, dlt);

        scan_kernel<<<BB * (DI / 16), 256, 0, stream>>>(
            dlt, xi, bcd, lA + (size_t)layer * DI * NS, Dp + (size_t)layer * DI, yb);

        gate_kernel<<<(BT * DI + 255) / 256, 256, 0, stream>>>(yb, xz, yg_bf);

        // h += y @ ow^T : M=2048 N=768 K=1536
        gemm_bf16<true, false, false><<<dim3(BT / 128, DD / 128, 1), 256, 0, stream>>>(
            yg_bf, ow_bf + (size_t)layer * DD * DI, h, DD, DI, DD, DI);
    }

    rmsnorm_kernel<<<BT, 256, 0, stream>>>(h, nfw, hn_bf);

    // logits = hn @ emb^T : M=2048 N=32000 K=768
    gemm_bf16<false, false, false><<<dim3(BT / 128, VOC / 128, 1), 256, 0, stream>>>(
        hn_bf, emb_bf, out, VOC, DD, VOC, DD);
}

// Round 3
// 921.842 us; speedup vs baseline: 1.8539x; 1.4421x over previous
//
#include <hip/hip_runtime.h>
#include <math.h>

#define BB 2
#define LL 1024
#define DD 768
#define DI 1536
#define NS 16
#define DRR 48
#define KC 4
#define VOC 32000
#define BT (BB*LL)          // 2048 rows
#define EPS 1e-5f

#define NCH 16              // scan chunks
#define TC  (LL/NCH)        // 64 timesteps per chunk
#define CHW ((DI/16)*256)   // elems per (b,chunk) in state bufs = 24576

typedef __attribute__((ext_vector_type(4))) float f32x4;
typedef __attribute__((ext_vector_type(8))) short short8;
typedef unsigned short ushort_t;

__device__ __forceinline__ unsigned short f2bf(float f) {
    unsigned int u = __float_as_uint(f);
    u += 0x7FFFu + ((u >> 16) & 1u);   // RNE
    return (unsigned short)(u >> 16);
}

// async global->LDS, 16B per lane; lds base must be wave-uniform, HW adds lane*16
#define GLDS(gp, lp) __builtin_amdgcn_global_load_lds( \
    (const __attribute__((address_space(1))) unsigned int*)(gp), \
    (__attribute__((address_space(3))) unsigned int*)(lp), 16, 0, 0)

// 16-lane (DPP row) sum reduction, all VALU-rate: quad_perm swaps + mirrors
#define DPP_ADD(c, ctrl) ((c) + __int_as_float(__builtin_amdgcn_update_dpp( \
    0, __float_as_int(c), (ctrl), 0xF, 0xF, true)))

// ---------------------------------------------------------------------------
// C = A(MxK,bf16) * W(NxK,bf16)^T [+C / atomic], fp32 out.
// m97 structure: 128x128 tile, BK=32, global_load_lds width-16 staging.
// ---------------------------------------------------------------------------
template<bool ADD, bool NMASK, bool ATOMIC>
__global__ __launch_bounds__(256) void gemm_bf16(
    const ushort_t* __restrict__ A, const ushort_t* __restrict__ W,
    float* C, int Nn, int lda, int ldc, int kchunk)
{
    __shared__ __align__(16) ushort_t As[128 * 32];
    __shared__ __align__(16) ushort_t Ws[128 * 32];

    const int row0 = blockIdx.x * 128;
    const int col0 = blockIdx.y * 128;
    const int tid  = threadIdx.x;
    const int lane = tid & 63;
    const int wave = tid >> 6;
    const int wm   = (wave & 1) * 64;
    const int wn   = (wave >> 1) * 64;
    const int mrow = lane & 15;
    const int quad = lane >> 4;

    const int kb = blockIdx.z * kchunk;

    const int srow = tid >> 2;
    const int scol = (tid & 3) << 3;
    const ushort_t* gA0 = A + (size_t)(row0 + srow) * lda + scol;
    const ushort_t* gA1 = A + (size_t)(row0 + 64 + srow) * lda + scol;
    const ushort_t* gW0 = W + (size_t)(col0 + srow) * lda + scol;
    const ushort_t* gW1 = W + (size_t)(col0 + 64 + srow) * lda + scol;
    char* lA0 = (char*)As + wave * 1024;
    char* lA1 = (char*)As + 4096 + wave * 1024;
    char* lW0 = (char*)Ws + wave * 1024;
    char* lW1 = (char*)Ws + 4096 + wave * 1024;

    f32x4 acc[4][4];
#pragma unroll
    for (int i = 0; i < 4; ++i)
#pragma unroll
        for (int j = 0; j < 4; ++j)
            acc[i][j] = (f32x4){0.f, 0.f, 0.f, 0.f};

    for (int k0 = kb; k0 < kb + kchunk; k0 += 32) {
        GLDS(gA0 + k0, lA0);
        GLDS(gA1 + k0, lA1);
        GLDS(gW0 + k0, lW0);
        GLDS(gW1 + k0, lW1);
        __syncthreads();

        short8 af[4], wf[4];
#pragma unroll
        for (int i = 0; i < 4; ++i) {
            af[i] = *(const short8*)&As[(wm + i * 16 + mrow) * 32 + quad * 8];
            wf[i] = *(const short8*)&Ws[(wn + i * 16 + mrow) * 32 + quad * 8];
        }
#pragma unroll
        for (int i = 0; i < 4; ++i)
#pragma unroll
            for (int j = 0; j < 4; ++j)
                acc[i][j] = __builtin_amdgcn_mfma_f32_16x16x32_bf16(
                    af[i], wf[j], acc[i][j], 0, 0, 0);
        __syncthreads();
    }

#pragma unroll
    for (int i = 0; i < 4; ++i)
#pragma unroll
        for (int j = 0; j < 4; ++j)
#pragma unroll
            for (int r = 0; r < 4; ++r) {
                int row = row0 + wm + i * 16 + quad * 4 + r;
                int col = col0 + wn + j * 16 + mrow;
                if (!NMASK || col < Nn) {
                    float v = acc[i][j][r];
                    size_t off = (size_t)row * ldc + col;
                    if (ATOMIC) {
                        atomicAdd(&C[off], v);
                    } else {
                        if (ADD) v += C[off];
                        C[off] = v;
                    }
                }
            }
}

// ---------------------------------------------------------------------------
__global__ __launch_bounds__(256) void cvt_bf16_kernel(
    const float* __restrict__ in, ushort_t* __restrict__ out, int n4)
{
    int i = blockIdx.x * 256 + threadIdx.x;
    if (i >= n4) return;
    float4 v = ((const float4*)in)[i];
    ushort4 o;
    o.x = f2bf(v.x); o.y = f2bf(v.y); o.z = f2bf(v.z); o.w = f2bf(v.w);
    ((ushort4*)out)[i] = o;
}

__global__ __launch_bounds__(256) void cvt_bcw_kernel(
    const float* __restrict__ bcw, ushort_t* __restrict__ out)
{
    int i = blockIdx.x * 256 + threadIdx.x;
    if (i >= 2 * 128 * 1536 / 4) return;
    int e = i * 4;
    int layer = e / (128 * 1536);
    int rem = e % (128 * 1536);
    int row = rem / 1536, col = rem % 1536;
    ushort4 o = {0, 0, 0, 0};
    if (row < 80) {
        float4 v = *(const float4*)(bcw + ((size_t)layer * 80 + row) * 1536 + col);
        o.x = f2bf(v.x); o.y = f2bf(v.y); o.z = f2bf(v.z); o.w = f2bf(v.w);
    }
    ((ushort4*)out)[i] = o;
}

__global__ __launch_bounds__(256) void zero_kernel(float* __restrict__ p, int n)
{
    int i = blockIdx.x * 256 + threadIdx.x;
    if (i < n) p[i] = 0.f;
}

// ---------------------------------------------------------------------------
__global__ __launch_bounds__(256) void embed_kernel(
    const int* __restrict__ x, const float* __restrict__ emb, float* __restrict__ h)
{
    int idx = blockIdx.x * 256 + threadIdx.x;
    if (idx >= BT * (DD / 4)) return;
    int row = idx / (DD / 4), c = idx % (DD / 4);
    ((float4*)h)[idx] = ((const float4*)(emb + (size_t)x[row] * DD))[c];
}

__global__ __launch_bounds__(256) void rmsnorm_kernel(
    const float* __restrict__ h, const float* __restrict__ w, ushort_t* __restrict__ out)
{
    int row = blockIdx.x, tid = threadIdx.x;
    const float* hr = h + (size_t)row * DD;
    float s = 0.f;
    for (int i = tid; i < DD; i += 256) { float v = hr[i]; s += v * v; }
#pragma unroll
    for (int off = 32; off >= 1; off >>= 1) s += __shfl_xor(s, off);
    __shared__ float part[4];
    if ((tid & 63) == 0) part[tid >> 6] = s;
    __syncthreads();
    float tot = part[0] + part[1] + part[2] + part[3];
    float sc = rsqrtf(tot * (1.0f / DD) + EPS);
    for (int i = tid; i < DD; i += 256)
        out[(size_t)row * DD + i] = f2bf(hr[i] * sc * w[i]);
}

__global__ __launch_bounds__(256) void conv_silu_kernel(
    const float* __restrict__ xz, const float* __restrict__ cw,
    const float* __restrict__ cb, float* __restrict__ xi, ushort_t* __restrict__ xi16)
{
    int idx = blockIdx.x * 256 + threadIdx.x;
    if (idx >= BT * DI) return;
    int d = idx % DI, bt = idx / DI, t = bt % LL;
    const float* base = xz + (size_t)bt * (2 * DI) + d;
    float w0 = cw[d * 4 + 0], w1 = cw[d * 4 + 1], w2 = cw[d * 4 + 2], w3 = cw[d * 4 + 3];
    float acc = cb[d] + base[0] * w3;
    if (t >= 1) acc += base[-(ptrdiff_t)(2 * DI)] * w2;
    if (t >= 2) acc += base[-(ptrdiff_t)(4 * DI)] * w1;
    if (t >= 3) acc += base[-(ptrdiff_t)(6 * DI)] * w0;
    float v = acc / (1.0f + expf(-acc));
    xi[idx] = v;
    xi16[idx] = f2bf(v);
}

__global__ __launch_bounds__(256) void delta_kernel(
    const float* __restrict__ bcd, const float* __restrict__ dw,
    const float* __restrict__ db, float* __restrict__ delta)
{
    int row = blockIdx.x / 6, chunk = blockIdx.x % 6;
    int d = chunk * 256 + threadIdx.x;
    __shared__ float dlt_s[DRR];
    if (threadIdx.x < DRR) dlt_s[threadIdx.x] = bcd[(size_t)row * 80 + 32 + threadIdx.x];
    __syncthreads();
    float z = db[d];
    const float* wr = dw + (size_t)d * DRR;
#pragma unroll
    for (int r = 0; r < DRR; ++r) z = fmaf(dlt_s[r], wr[r], z);
    delta[(size_t)row * DI + d] = (z > 20.f) ? z : log1pf(expf(z));
}

// ---------------------------------------------------------------------------
// Chunked S6 scan. Pass 1: per-chunk local scan from h=0 -> (A_cum, h_end).
// Pass 2: sequential combine over chunks -> h_init. Pass 3: local scan from
// h_init, DPP row-reduction for y.
// blockIdx.x = (b*(DI/16) + dbi)*NCH + c ; thread: n=lane&15, dl=wave*4+lane>>4
// ---------------------------------------------------------------------------
__global__ __launch_bounds__(256) void scan_pass1(
    const float* __restrict__ delta, const float* __restrict__ xi,
    const float* __restrict__ bcd, const float* __restrict__ lA,
    float* __restrict__ a_cum, float* __restrict__ h_end)
{
    int blk  = blockIdx.x;
    int c    = blk % NCH;
    int rest = blk / NCH;
    int b    = rest / (DI / 16);
    int dbi  = rest % (DI / 16);
    int dblk = dbi * 16;
    int tid  = threadIdx.x, lane = tid & 63, wave = tid >> 6;
    int n = lane & 15, dl = wave * 4 + (lane >> 4), d = dblk + dl;

    float Av   = -expf(lA[(size_t)d * NS + n]);
    float A2   = Av * 1.44269504088896f;
    float invA = 1.0f / Av;

    __shared__ float2 s_dx[TC][16];
    __shared__ float  s_B [TC][16];

    const float* dbase = delta + ((size_t)b * LL + c * TC) * DI + dblk;
    const float* xbase = xi    + ((size_t)b * LL + c * TC) * DI + dblk;
    const float* bcb   = bcd   + ((size_t)b * LL + c * TC) * 80;

    for (int i = tid; i < TC * 16; i += 256) {
        int tt = i >> 4, dd = i & 15;
        s_dx[tt][dd] = make_float2(dbase[(size_t)tt * DI + dd],
                                   xbase[(size_t)tt * DI + dd]);
        s_B[tt][dd]  = bcb[(size_t)tt * 80 + dd];
    }
    __syncthreads();

    float hs = 0.f, sd = 0.f;
#pragma unroll 4
    for (int tt = 0; tt < TC; ++tt) {
        float2 dx = s_dx[tt][dl];
        float Bv  = s_B[tt][n];
        float Ab  = exp2f(dx.x * A2);
        float u   = (Ab - 1.0f) * invA * Bv * dx.y;
        hs = fmaf(Ab, hs, u);
        sd += dx.x;
    }
    size_t o = (((size_t)b * NCH + c) * (DI / 16) + dbi) * 256 + dl * 16 + n;
    a_cum[o] = exp2f(A2 * sd);
    h_end[o] = hs;
}

__global__ __launch_bounds__(256) void scan_pass2(
    const float* __restrict__ a_cum, const float* __restrict__ h_end,
    float* __restrict__ h_init)
{
    int gid = blockIdx.x * 256 + threadIdx.x;   // over BB * CHW
    if (gid >= BB * CHW) return;
    int b = gid / CHW, r = gid % CHW;
    size_t base = (size_t)b * NCH * CHW + r;
    float h = 0.f;
#pragma unroll
    for (int c = 0; c < NCH; ++c) {
        h_init[base + (size_t)c * CHW] = h;
        h = fmaf(a_cum[base + (size_t)c * CHW], h, h_end[base + (size_t)c * CHW]);
    }
}

__global__ __launch_bounds__(256) void scan_pass3(
    const float* __restrict__ delta, const float* __restrict__ xi,
    const float* __restrict__ bcd, const float* __restrict__ lA,
    const float* __restrict__ Dp, const float* __restrict__ h_init,
    float* __restrict__ y)
{
    int blk  = blockIdx.x;
    int c    = blk % NCH;
    int rest = blk / NCH;
    int b    = rest / (DI / 16);
    int dbi  = rest % (DI / 16);
    int dblk = dbi * 16;
    int tid  = threadIdx.x, lane = tid & 63, wave = tid >> 6;
    int n = lane & 15, dl = wave * 4 + (lane >> 4), d = dblk + dl;

    float Av   = -expf(lA[(size_t)d * NS + n]);
    float A2   = Av * 1.44269504088896f;
    float invA = 1.0f / Av;
    float Dpv  = Dp[d];

    __shared__ float2 s_dx[TC][16];
    __shared__ float2 s_bc[TC][16];

    const float* dbase = delta + ((size_t)b * LL + c * TC) * DI + dblk;
    const float* xbase = xi    + ((size_t)b * LL + c * TC) * DI + dblk;
    const float* bcb   = bcd   + ((size_t)b * LL + c * TC) * 80;
    float*       ybase = y     + ((size_t)b * LL + c * TC) * DI + dblk;

    for (int i = tid; i < TC * 16; i += 256) {
        int tt = i >> 4, dd = i & 15;
        s_dx[tt][dd] = make_float2(dbase[(size_t)tt * DI + dd],
                                   xbase[(size_t)tt * DI + dd]);
        s_bc[tt][dd] = make_float2(bcb[(size_t)tt * 80 + dd],
                                   bcb[(size_t)tt * 80 + 16 + dd]);
    }
    __syncthreads();

    float hs = h_init[(((size_t)b * NCH + c) * (DI / 16) + dbi) * 256 + dl * 16 + n];

#pragma unroll 4
    for (int tt = 0; tt < TC; ++tt) {
        float2 dx = s_dx[tt][dl];
        float2 bc = s_bc[tt][n];
        float Ab  = exp2f(dx.x * A2);
        float u   = (Ab - 1.0f) * invA * bc.x * dx.y;
        hs = fmaf(Ab, hs, u);
        float r = bc.y * hs;
        r = DPP_ADD(r, 0xB1);    // + lane^1 (quad_perm [1,0,3,2])
        r = DPP_ADD(r, 0x4E);    // + lane^2 (quad_perm [2,3,0,1])
        r = DPP_ADD(r, 0x141);   // + row_half_mirror (8-lane fold)
        r = DPP_ADD(r, 0x140);   // + row_mirror (16-lane fold)
        if (n == 0) ybase[(size_t)tt * DI + dl] = fmaf(dx.y, Dpv, r);
    }
}

// yg16 = bf16( y * silu(xz[:, DI:2*DI]) )
__global__ __launch_bounds__(256) void gate_kernel(
    const float* __restrict__ y, const float* __restrict__ xz, ushort_t* __restrict__ yg16)
{
    int idx = blockIdx.x * 256 + threadIdx.x;
    if (idx >= BT * DI) return;
    int d = idx % DI, bt = idx / DI;
    float r = xz[(size_t)bt * (2 * DI) + DI + d];
    yg16[idx] = f2bf(y[idx] * r / (1.0f + expf(-r)));
}

// ---------------------------------------------------------------------------
extern "C" void kernel_launch(void* const* d_in, const int* in_sizes, int n_in,
                              void* d_out, int out_size, void* d_ws, size_t ws_size,
                              hipStream_t stream)
{
    const int*   x    = (const int*)  d_in[0];
    const float* emb  = (const float*)d_in[1];
    const float* rmsw = (const float*)d_in[2];
    const float* inw  = (const float*)d_in[3];
    const float* cw   = (const float*)d_in[4];
    const float* cb   = (const float*)d_in[5];
    const float* lA   = (const float*)d_in[6];
    const float* bcw  = (const float*)d_in[7];
    const float* dw   = (const float*)d_in[8];
    const float* db   = (const float*)d_in[9];
    const float* Dp   = (const float*)d_in[10];
    const float* ow   = (const float*)d_in[11];
    const float* nfw  = (const float*)d_in[12];
    float* out = (float*)d_out;

    float* ws = (float*)d_ws;
    float* h    = ws;                          // BT*DD
    float* xz   = h    + (size_t)BT * DD;      // BT*2*DI
    float* xi   = xz   + (size_t)BT * 2 * DI;  // BT*DI
    float* bcd  = xi   + (size_t)BT * DI;      // BT*80
    float* dlt  = bcd  + (size_t)BT * 80;      // BT*DI
    float* yb   = dlt  + (size_t)BT * DI;      // BT*DI
    float* acum = yb   + (size_t)BT * DI;      // BB*NCH*DI*NS
    float* hend = acum + (size_t)BB * NCH * DI * NS;
    float* hini = hend + (size_t)BB * NCH * DI * NS;
    ushort_t* bf = (ushort_t*)(hini + (size_t)BB * NCH * DI * NS);
    ushort_t* hn_bf  = bf;                                  // BT*DD
    ushort_t* xib_bf = hn_bf  + (size_t)BT * DD;            // BT*DI
    ushort_t* yg_bf  = xib_bf + (size_t)BT * DI;            // BT*DI
    ushort_t* emb_bf = yg_bf  + (size_t)BT * DI;            // VOC*DD
    ushort_t* inw_bf = emb_bf + (size_t)VOC * DD;           // 2*2DI*DD
    ushort_t* ow_bf  = inw_bf + (size_t)2 * 2 * DI * DD;    // 2*DD*DI
    ushort_t* bcw_bf = ow_bf  + (size_t)2 * DD * DI;        // 2*128*1536

    cvt_bf16_kernel<<<(VOC * DD / 4 + 255) / 256, 256, 0, stream>>>(emb, emb_bf, VOC * DD / 4);
    cvt_bf16_kernel<<<(2 * 2 * DI * DD / 4 + 255) / 256, 256, 0, stream>>>(inw, inw_bf, 2 * 2 * DI * DD / 4);
    cvt_bf16_kernel<<<(2 * DD * DI / 4 + 255) / 256, 256, 0, stream>>>(ow, ow_bf, 2 * DD * DI / 4);
    cvt_bcw_kernel<<<(2 * 128 * 1536 / 4 + 255) / 256, 256, 0, stream>>>(bcw, bcw_bf);

    embed_kernel<<<(BT * (DD / 4) + 255) / 256, 256, 0, stream>>>(x, emb, h);

    for (int layer = 0; layer < 2; ++layer) {
        rmsnorm_kernel<<<BT, 256, 0, stream>>>(h, rmsw + (size_t)layer * DD, hn_bf);

        // xz = hn @ in_w^T : M=2048 N=3072 K=768
        gemm_bf16<false, false, false><<<dim3(BT / 128, 2 * DI / 128, 1), 256, 0, stream>>>(
            hn_bf, inw_bf + (size_t)layer * 2 * DI * DD, xz, 2 * DI, DD, 2 * DI, DD);

        conv_silu_kernel<<<(BT * DI + 255) / 256, 256, 0, stream>>>(
            xz, cw + (size_t)layer * DI * KC, cb + (size_t)layer * DI, xi, xib_bf);

        zero_kernel<<<(BT * 80 + 255) / 256, 256, 0, stream>>>(bcd, BT * 80);

        // bcd = xi @ bcw^T : M=2048 N=80(pad128) K=1536, split-K=8
        gemm_bf16<false, true, true><<<dim3(BT / 128, 1, 8), 256, 0, stream>>>(
            xib_bf, bcw_bf + (size_t)layer * 128 * 1536, bcd, 80, DI, 80, DI / 8);

        delta_kernel<<<BT * 6, 256, 0, stream>>>(
            bcd, dw + (size_t)layer * DI * DRR, db + (size_t)layer * DI, dlt);

        scan_pass1<<<BB * (DI / 16) * NCH, 256, 0, stream>>>(
            dlt, xi, bcd, lA + (size_t)layer * DI * NS, acum, hend);
        scan_pass2<<<(BB * CHW + 255) / 256, 256, 0, stream>>>(acum, hend, hini);
        scan_pass3<<<BB * (DI / 16) * NCH, 256, 0, stream>>>(
            dlt, xi, bcd, lA + (size_t)layer * DI * NS, Dp + (size_t)layer * DI, hini, yb);

        gate_kernel<<<(BT * DI + 255) / 256, 256, 0, stream>>>(yb, xz, yg_bf);

        // h += y @ ow^T : M=2048 N=768 K=1536
        gemm_bf16<true, false, false><<<dim3(BT / 128, DD / 128, 1), 256, 0, stream>>>(
            yg_bf, ow_bf + (size_t)layer * DD * DI, h, DD, DI, DD, DI);
    }

    rmsnorm_kernel<<<BT, 256, 0, stream>>>(h, nfw, hn_bf);

    // logits = hn @ emb^T : M=2048 N=32000 K=768
    gemm_bf16<false, false, false><<<dim3(BT / 128, VOC / 128, 1), 256, 0, stream>>>(
        hn_bf, emb_bf, out, VOC, DD, VOC, DD);
}